// Round 9
// baseline (1657.602 us; speedup 1.0000x reference)
//
#include <hip/hip_runtime.h>
#include <hip/hip_bf16.h>
#include <math.h>

// ---------------------------------------------------------------------------
// GCN: 4 x [h = tanh(Dis (A+I) Dis (x W) + b)], then h @ W_out + b_out
// N=100k nodes, E=1M edges, D=64, D_OUT=16, all fp32.
// Setup: bucket partition (packed u32) -> LDS degrees -> CSR fill (LDS cursors),
//        srcl entries carry dst-local-64 in bits 17..22.
// Layers: gemm2 (MFMA bf16 3-term split) for layer 0, then fused
//        EDGE-PARALLEL agg (LDS float atomics) + MFMA gemm per layer;
//        final layer: edge-parallel agg + MFMA 64->16 projection.
// ---------------------------------------------------------------------------

#define NBSHIFT 9   // bucket = dst >> 9  (512 nodes/bucket)

typedef __attribute__((ext_vector_type(8))) short short8;
typedef __attribute__((ext_vector_type(4))) float f32x4;

__device__ __forceinline__ float tanh_fast(float x) {
    float e = __expf(2.0f * x);
    return 1.0f - 2.0f / (e + 1.0f);
}
__device__ __forceinline__ unsigned short f2bf(float f) {   // RNE float->bf16
    unsigned u = __float_as_uint(f);
    return (unsigned short)((u + 0x7fff + ((u >> 16) & 1)) >> 16);
}
__device__ __forceinline__ float bf2f(unsigned short h) {
    return __uint_as_float((unsigned)h << 16);
}

// ---- generic 3-phase exclusive scan ----------------------------------------
__global__ void __launch_bounds__(1024) scan1_kernel(const int* __restrict__ in,
                                                     int* __restrict__ out,
                                                     int* __restrict__ csum, int n) {
    __shared__ int s[1024];
    int t = threadIdx.x;
    int i = blockIdx.x * 1024 + t;
    int v = (i < n) ? in[i] : 0;
    s[t] = v;
    __syncthreads();
    #pragma unroll
    for (int o = 1; o < 1024; o <<= 1) {
        int a = 0;
        if (t >= o) a = s[t - o];
        __syncthreads();
        if (t >= o) s[t] += a;
        __syncthreads();
    }
    if (i < n) out[i] = s[t] - v;          // exclusive
    if (t == 1023) csum[blockIdx.x] = s[1023];
}

__global__ void __launch_bounds__(1024) scan2_kernel(int* __restrict__ csum, int nc) {
    __shared__ int s[1024];
    int t = threadIdx.x;
    int v = (t < nc) ? csum[t] : 0;
    s[t] = v;
    __syncthreads();
    #pragma unroll
    for (int o = 1; o < 1024; o <<= 1) {
        int a = 0;
        if (t >= o) a = s[t - o];
        __syncthreads();
        if (t >= o) s[t] += a;
        __syncthreads();
    }
    if (t < nc) csum[t] = s[t] - v;        // exclusive
}

__global__ void __launch_bounds__(1024) scan3_kernel(int* __restrict__ out,
                                                     const int* __restrict__ csum,
                                                     int n, int total) {
    int i = blockIdx.x * 1024 + threadIdx.x;
    if (i < n) out[i] += csum[blockIdx.x];
    if (i == 0) out[n] = total;            // sentinel
}

// ---- bucket histogram ------------------------------------------------------
__global__ void __launch_bounds__(256) hist_kernel(const int* __restrict__ dst,
                                                   int* __restrict__ hist,
                                                   int E, int NB, int nblocks) {
    __shared__ int lh[256];
    int t = threadIdx.x;
    lh[t] = 0;
    __syncthreads();
    int base = blockIdx.x * 4096;
    int end = base + 4096; if (end > E) end = E;
    for (int i = base + t; i < end; i += 256)
        atomicAdd(&lh[dst[i] >> NBSHIFT], 1);
    __syncthreads();
    if (t < NB) hist[t * nblocks + blockIdx.x] = lh[t];
}

// ---- partition edges into bucket-major staging (packed u32) ----------------
// record = (local_dst[9b] << 17) | src[17b]   (N < 131072)
__global__ void __launch_bounds__(256) part_kernel(const int* __restrict__ src,
                                                   const int* __restrict__ dst,
                                                   const int* __restrict__ phist,
                                                   unsigned* __restrict__ staged,
                                                   int E, int NB, int nblocks) {
    __shared__ int lcur[256];
    int t = threadIdx.x;
    if (t < NB) lcur[t] = phist[t * nblocks + blockIdx.x];
    __syncthreads();
    int base = blockIdx.x * 4096;
    int end = base + 4096; if (end > E) end = E;
    for (int i = base + t; i < end; i += 256) {
        int d = dst[i];
        int b = d >> NBSHIFT;
        int pos = atomicAdd(&lcur[b], 1);
        staged[pos] = ((unsigned)(d & 511) << 17) | (unsigned)src[i];
    }
}

// ---- per-bucket degree count in LDS + dis = rsqrt(deg+1) -------------------
__global__ void __launch_bounds__(256) bdeg_kernel(const unsigned* __restrict__ staged,
                                                   const int* __restrict__ phist,
                                                   int* __restrict__ deg,
                                                   float* __restrict__ dis,
                                                   int nblocks, int n) {
    __shared__ int ldeg[512];
    int b = blockIdx.x, t = threadIdx.x;
    ldeg[t] = 0; ldeg[t + 256] = 0;
    __syncthreads();
    int r0 = phist[b * nblocks];
    int r1 = phist[(b + 1) * nblocks];
    for (int i = r0 + t; i < r1; i += 256)
        atomicAdd(&ldeg[staged[i] >> 17], 1);
    __syncthreads();
    int gbase = b << NBSHIFT;
    #pragma unroll
    for (int k = 0; k < 2; ++k) {
        int li = t + k * 256, gi = gbase + li;
        if (gi < n) {
            int d = ldeg[li];
            deg[gi] = d;
            dis[gi] = rsqrtf((float)d + 1.0f);
        }
    }
}

// ---- per-bucket CSR fill with LDS cursors ----------------------------------
// srcl entry = (dst&63)<<17 | src   (dst-local within any 64-aligned block)
__global__ void __launch_bounds__(256) fill3_kernel(const unsigned* __restrict__ staged,
                                                    const int* __restrict__ phist,
                                                    const int* __restrict__ off,
                                                    int* __restrict__ srcl,
                                                    int nblocks, int n) {
    __shared__ int lcur[512];
    int b = blockIdx.x, t = threadIdx.x;
    int gbase = b << NBSHIFT;
    #pragma unroll
    for (int k = 0; k < 2; ++k) {
        int li = t + k * 256, gi = gbase + li;
        lcur[li] = (gi < n) ? off[gi] : 0;
    }
    __syncthreads();
    int r0 = phist[b * nblocks];
    int r1 = phist[(b + 1) * nblocks];
    for (int i = r0 + t; i < r1; i += 256) {
        unsigned rec = staged[i];
        unsigned local9 = rec >> 17;
        int pos = atomicAdd(&lcur[local9], 1);
        srcl[pos] = (int)(((local9 & 63u) << 17) | (rec & 0x1FFFFu));
    }
}

// ---- W fragment prep: bf16 hi/lo frags arranged frag-major -----------------
__global__ void __launch_bounds__(256) wprep_kernel(const float* __restrict__ W0,
                                                    const float* __restrict__ W1,
                                                    const float* __restrict__ W2,
                                                    const float* __restrict__ W3,
                                                    short* __restrict__ wf) {
    const float* Ws[4] = {W0, W1, W2, W3};
    int l = blockIdx.x;
    const float* Wg = Ws[l];
    int t = threadIdx.x;
    int lane = t & 63;
    int ct = t >> 6;
    #pragma unroll
    for (int kk = 0; kk < 2; ++kk) {
        #pragma unroll
        for (int e = 0; e < 8; ++e) {
            int k = kk * 32 + (lane >> 4) * 8 + e;
            int c = ct * 16 + (lane & 15);
            float w = Wg[k * 64 + c];
            unsigned short hi = f2bf(w);
            unsigned short lo = f2bf(w - bf2f(hi));
            size_t b = ((size_t)l * 4 + ct) * 2 + kk;
            wf[((b * 2 + 0) * 64 + lane) * 8 + e] = (short)hi;
            wf[((b * 2 + 1) * 64 + lane) * 8 + e] = (short)lo;
        }
    }
}

// ---- W_out fragment prep (64x16, single col-tile), blocks 64..67 -----------
__global__ void __launch_bounds__(64) wprep_out_kernel(const float* __restrict__ Wo,
                                                       short* __restrict__ wf) {
    int lane = threadIdx.x & 63;
    #pragma unroll
    for (int kk = 0; kk < 2; ++kk) {
        #pragma unroll
        for (int e = 0; e < 8; ++e) {
            int k = kk * 32 + (lane >> 4) * 8 + e;
            int c = lane & 15;
            float w = Wo[k * 16 + c];
            unsigned short hi = f2bf(w);
            unsigned short lo = f2bf(w - bf2f(hi));
            size_t b = 32 + kk;            // after 4 layers x 4ct x 2kk
            wf[((b * 2 + 0) * 64 + lane) * 8 + e] = (short)hi;
            wf[((b * 2 + 1) * 64 + lane) * 8 + e] = (short)lo;
        }
    }
}

// ---- bf16 split helper -----------------------------------------------------
#define SPLIT8(vA, vB, H, L) { \
    float _f[8] = {vA.x, vA.y, vA.z, vA.w, vB.x, vB.y, vB.z, vB.w}; \
    _Pragma("unroll") \
    for (int _e = 0; _e < 8; ++_e) { \
        unsigned short _h = f2bf(_f[_e]); \
        H[_e] = (short)_h; \
        L[_e] = (short)f2bf(_f[_e] - bf2f(_h)); \
    } }

// ---- MFMA gemm (layer 0): g[n][d] = dis[n] * sum_k x[n][k] * W[k][d] -------
__global__ void __launch_bounds__(256) gemm2_kernel(const float* __restrict__ in,
                                                    const short* __restrict__ wf,
                                                    const float* __restrict__ dis,
                                                    float* __restrict__ g, int n) {
    int t = threadIdx.x;
    int lane = t & 63;
    int wave = t >> 6;
    int c = lane & 15;
    int g4 = lane >> 4;

    short8 Bh[4][2], Bl[4][2];
    #pragma unroll
    for (int ct = 0; ct < 4; ++ct) {
        #pragma unroll
        for (int kk = 0; kk < 2; ++kk) {
            int b = (ct * 2 + kk) * 2;
            Bh[ct][kk] = *(const short8*)(wf + ((size_t)(b + 0) * 64 + lane) * 8);
            Bl[ct][kk] = *(const short8*)(wf + ((size_t)(b + 1) * 64 + lane) * 8);
        }
    }

    int tile = blockIdx.x * 4 + wave;
    int base = tile * 16;
    if (base >= n) return;

    const float4* ap = (const float4*)(in + (size_t)(base + c) * 64 + g4 * 8);
    float4 v00 = ap[0], v01 = ap[1];
    float4 v10 = ap[8], v11 = ap[9];

    short8 Ah0, Al0, Ah1, Al1;
    SPLIT8(v00, v01, Ah0, Al0);
    SPLIT8(v10, v11, Ah1, Al1);

    f32x4 acc[4];
    #pragma unroll
    for (int ct = 0; ct < 4; ++ct) {
        f32x4 a = {0.f, 0.f, 0.f, 0.f};
        a = __builtin_amdgcn_mfma_f32_16x16x32_bf16(Ah0, Bh[ct][0], a, 0, 0, 0);
        a = __builtin_amdgcn_mfma_f32_16x16x32_bf16(Ah1, Bh[ct][1], a, 0, 0, 0);
        a = __builtin_amdgcn_mfma_f32_16x16x32_bf16(Al0, Bh[ct][0], a, 0, 0, 0);
        a = __builtin_amdgcn_mfma_f32_16x16x32_bf16(Al1, Bh[ct][1], a, 0, 0, 0);
        a = __builtin_amdgcn_mfma_f32_16x16x32_bf16(Ah0, Bl[ct][0], a, 0, 0, 0);
        a = __builtin_amdgcn_mfma_f32_16x16x32_bf16(Ah1, Bl[ct][1], a, 0, 0, 0);
        acc[ct] = a;
    }

    f32x4 dvv = *(const f32x4*)(dis + base + g4 * 4);
    #pragma unroll
    for (int ct = 0; ct < 4; ++ct) {
        #pragma unroll
        for (int r = 0; r < 4; ++r) {
            g[(size_t)(base + g4 * 4 + r) * 64 + ct * 16 + c] = dvv[r] * acc[ct][r];
        }
    }
}

// ---- shared agg phase: edge-parallel gather into hs via LDS atomics --------
// hs[nl] ends with tanh(dis*(self+neigh)+bias) for the 64 nodes of the block.
__device__ __forceinline__ void agg_phase(float (*hs)[68],
                                          const float* __restrict__ g_in,
                                          const float* __restrict__ dis,
                                          const int* __restrict__ off,
                                          const int* __restrict__ srcl,
                                          const float* __restrict__ bias,
                                          int base, int n, int t) {
    int r = t & 15;                        // lane-in-quarter (float4 column)
    int qq = t >> 4;                       // quarter 0..15
    const float4* gv = (const float4*)g_in;

    // self-term init
    #pragma unroll
    for (int p = 0; p < 4; ++p) {
        int nl = p * 16 + qq;
        int node = base + nl;
        if (node < n) {
            float4 sv = gv[(size_t)node * 16 + r];
            hs[nl][r * 4 + 0] = sv.x;
            hs[nl][r * 4 + 1] = sv.y;
            hs[nl][r * 4 + 2] = sv.z;
            hs[nl][r * 4 + 3] = sv.w;
        }
    }
    __syncthreads();

    // edge-parallel gather: quarter qq takes edges e0+qq, e0+qq+16, ...
    int hi2 = base + 64; if (hi2 > n) hi2 = n;
    int e0 = off[base], e1 = off[hi2];
    for (int i = e0 + qq; i < e1; i += 16) {
        unsigned rec = (unsigned)srcl[i];
        int src = (int)(rec & 0x1FFFFu);
        int dl = (int)(rec >> 17);
        float4 a = gv[(size_t)src * 16 + r];
        atomicAdd(&hs[dl][r * 4 + 0], a.x);
        atomicAdd(&hs[dl][r * 4 + 1], a.y);
        atomicAdd(&hs[dl][r * 4 + 2], a.z);
        atomicAdd(&hs[dl][r * 4 + 3], a.w);
    }
    __syncthreads();

    // transform: tanh(dn*sum + b)
    float4 b4 = ((const float4*)bias)[r];
    #pragma unroll
    for (int p = 0; p < 4; ++p) {
        int nl = p * 16 + qq;
        int node = base + nl;
        if (node < n) {
            float dn = dis[node];
            hs[nl][r * 4 + 0] = tanh_fast(fmaf(dn, hs[nl][r * 4 + 0], b4.x));
            hs[nl][r * 4 + 1] = tanh_fast(fmaf(dn, hs[nl][r * 4 + 1], b4.y));
            hs[nl][r * 4 + 2] = tanh_fast(fmaf(dn, hs[nl][r * 4 + 2], b4.z));
            hs[nl][r * 4 + 3] = tanh_fast(fmaf(dn, hs[nl][r * 4 + 3], b4.w));
        }
    }
    __syncthreads();
}

// ---- fused: agg -> g_{l+1} = dis * (h @ W) via MFMA ------------------------
__global__ void __launch_bounds__(256) fused_kernel(const float* __restrict__ g_in,
                                                    const float* __restrict__ dis,
                                                    const int* __restrict__ off,
                                                    const int* __restrict__ srcl,
                                                    const float* __restrict__ bias,
                                                    const short* __restrict__ wfn,
                                                    float* __restrict__ g_out, int n) {
    __shared__ float hs[64][68];
    int t = threadIdx.x;
    int base = blockIdx.x * 64;

    agg_phase(hs, g_in, dis, off, srcl, bias, base, n, t);

    int lane = t & 63;
    int wave = t >> 6;
    int c = lane & 15;
    int g4 = lane >> 4;
    int obase = base + wave * 16;
    if (obase >= n) return;

    short8 Bh[4][2], Bl[4][2];
    #pragma unroll
    for (int ct = 0; ct < 4; ++ct) {
        #pragma unroll
        for (int kk = 0; kk < 2; ++kk) {
            int b = (ct * 2 + kk) * 2;
            Bh[ct][kk] = *(const short8*)(wfn + ((size_t)(b + 0) * 64 + lane) * 8);
            Bl[ct][kk] = *(const short8*)(wfn + ((size_t)(b + 1) * 64 + lane) * 8);
        }
    }

    const float* hr = &hs[wave * 16 + c][0];
    float4 v00 = *(const float4*)(hr + g4 * 8);
    float4 v01 = *(const float4*)(hr + g4 * 8 + 4);
    float4 v10 = *(const float4*)(hr + g4 * 8 + 32);
    float4 v11 = *(const float4*)(hr + g4 * 8 + 36);

    short8 Ah0, Al0, Ah1, Al1;
    SPLIT8(v00, v01, Ah0, Al0);
    SPLIT8(v10, v11, Ah1, Al1);

    f32x4 acc[4];
    #pragma unroll
    for (int ct = 0; ct < 4; ++ct) {
        f32x4 a = {0.f, 0.f, 0.f, 0.f};
        a = __builtin_amdgcn_mfma_f32_16x16x32_bf16(Ah0, Bh[ct][0], a, 0, 0, 0);
        a = __builtin_amdgcn_mfma_f32_16x16x32_bf16(Ah1, Bh[ct][1], a, 0, 0, 0);
        a = __builtin_amdgcn_mfma_f32_16x16x32_bf16(Al0, Bh[ct][0], a, 0, 0, 0);
        a = __builtin_amdgcn_mfma_f32_16x16x32_bf16(Al1, Bh[ct][1], a, 0, 0, 0);
        a = __builtin_amdgcn_mfma_f32_16x16x32_bf16(Ah0, Bl[ct][0], a, 0, 0, 0);
        a = __builtin_amdgcn_mfma_f32_16x16x32_bf16(Ah1, Bl[ct][1], a, 0, 0, 0);
        acc[ct] = a;
    }

    f32x4 dvv = *(const f32x4*)(dis + obase + g4 * 4);
    #pragma unroll
    for (int ct = 0; ct < 4; ++ct) {
        #pragma unroll
        for (int rr = 0; rr < 4; ++rr) {
            g_out[(size_t)(obase + g4 * 4 + rr) * 64 + ct * 16 + c] = dvv[rr] * acc[ct][rr];
        }
    }
}

// ---- fused final: agg(layer 3) -> out = h @ Wo + bo via MFMA ---------------
__global__ void __launch_bounds__(256) fused_final_kernel(const float* __restrict__ g_in,
                                                          const float* __restrict__ dis,
                                                          const int* __restrict__ off,
                                                          const int* __restrict__ srcl,
                                                          const float* __restrict__ bias,
                                                          const short* __restrict__ wf,
                                                          const float* __restrict__ bo,
                                                          float* __restrict__ out, int n) {
    __shared__ float hs[64][68];
    int t = threadIdx.x;
    int base = blockIdx.x * 64;

    agg_phase(hs, g_in, dis, off, srcl, bias, base, n, t);

    int lane = t & 63;
    int wave = t >> 6;
    int c = lane & 15;
    int g4 = lane >> 4;
    int obase = base + wave * 16;
    if (obase >= n) return;

    short8 Bh2[2], Bl2[2];
    #pragma unroll
    for (int kk = 0; kk < 2; ++kk) {
        size_t b = 32 + kk;
        Bh2[kk] = *(const short8*)(wf + ((b * 2 + 0) * 64 + lane) * 8);
        Bl2[kk] = *(const short8*)(wf + ((b * 2 + 1) * 64 + lane) * 8);
    }

    const float* hr = &hs[wave * 16 + c][0];
    float4 v00 = *(const float4*)(hr + g4 * 8);
    float4 v01 = *(const float4*)(hr + g4 * 8 + 4);
    float4 v10 = *(const float4*)(hr + g4 * 8 + 32);
    float4 v11 = *(const float4*)(hr + g4 * 8 + 36);

    short8 Ah0, Al0, Ah1, Al1;
    SPLIT8(v00, v01, Ah0, Al0);
    SPLIT8(v10, v11, Ah1, Al1);

    float bv = bo[c];
    f32x4 a = {bv, bv, bv, bv};
    a = __builtin_amdgcn_mfma_f32_16x16x32_bf16(Ah0, Bh2[0], a, 0, 0, 0);
    a = __builtin_amdgcn_mfma_f32_16x16x32_bf16(Ah1, Bh2[1], a, 0, 0, 0);
    a = __builtin_amdgcn_mfma_f32_16x16x32_bf16(Al0, Bh2[0], a, 0, 0, 0);
    a = __builtin_amdgcn_mfma_f32_16x16x32_bf16(Al1, Bh2[1], a, 0, 0, 0);
    a = __builtin_amdgcn_mfma_f32_16x16x32_bf16(Ah0, Bl2[0], a, 0, 0, 0);
    a = __builtin_amdgcn_mfma_f32_16x16x32_bf16(Ah1, Bl2[1], a, 0, 0, 0);

    #pragma unroll
    for (int rr = 0; rr < 4; ++rr) {
        out[(size_t)(obase + g4 * 4 + rr) * 16 + c] = a[rr];
    }
}

// ---------------------------------------------------------------------------
extern "C" void kernel_launch(void* const* d_in, const int* in_sizes, int n_in,
                              void* d_out, int out_size, void* d_ws, size_t ws_size,
                              hipStream_t stream) {
    const float* x     = (const float*)d_in[0];
    const int*   ei    = (const int*)d_in[1];   // (2, E) int32
    const float* W[4]  = {(const float*)d_in[2], (const float*)d_in[4],
                          (const float*)d_in[6], (const float*)d_in[8]};
    const float* B[4]  = {(const float*)d_in[3], (const float*)d_in[5],
                          (const float*)d_in[7], (const float*)d_in[9]};
    const float* Wo    = (const float*)d_in[10];
    const float* bo    = (const float*)d_in[11];
    float* out         = (float*)d_out;

    const int N = in_sizes[0] / 64;
    const int E = in_sizes[1] / 2;
    const int* srcp = ei;
    const int* dstp = ei + E;

    const int NB       = (N + (1 << NBSHIFT) - 1) >> NBSHIFT;  // 196
    const int nblocksP = (E + 4095) / 4096;                    // 245
    const int NH       = NB * nblocksP;

    char* w = (char*)d_ws;
    size_t o = 0;
    auto alloc = [&](size_t bytes) { void* p = w + o; o = (o + bytes + 255) & ~(size_t)255; return p; };
    float*    dis    = (float*)alloc((size_t)N * 4);
    int*      degi   = (int*)  alloc((size_t)N * 4);
    int*      off    = (int*)  alloc((size_t)(N + 1) * 4);
    int*      csum   = (int*)  alloc(4096);
    int*      srcl   = (int*)  alloc((size_t)E * 4);
    int*      hist   = (int*)  alloc((size_t)NH * 4);
    int*      phist  = (int*)  alloc((size_t)(NH + 1) * 4);
    short*    wf     = (short*)alloc((size_t)70 * 1024);      // 68 x 1KB frag blocks
    float*    bufA   = (float*)alloc((size_t)N * 64 * 4);
    float*    bufB   = (float*)alloc((size_t)N * 64 * 4);
    unsigned* staged = (unsigned*)bufA;    // reuse (4MB < 25.6MB), consumed pre-gemm

    int nchN = (N + 1023) / 1024;
    int nchH = (NH + 1023) / 1024;

    wprep_kernel<<<4, 256, 0, stream>>>(W[0], W[1], W[2], W[3], wf);
    wprep_out_kernel<<<1, 64, 0, stream>>>(Wo, wf);
    hist_kernel<<<nblocksP, 256, 0, stream>>>(dstp, hist, E, NB, nblocksP);
    scan1_kernel<<<nchH, 1024, 0, stream>>>(hist, phist, csum, NH);
    scan2_kernel<<<1, 1024, 0, stream>>>(csum, nchH);
    scan3_kernel<<<nchH, 1024, 0, stream>>>(phist, csum, NH, E);
    part_kernel<<<nblocksP, 256, 0, stream>>>(srcp, dstp, phist, staged, E, NB, nblocksP);
    bdeg_kernel<<<NB, 256, 0, stream>>>(staged, phist, degi, dis, nblocksP, N);
    scan1_kernel<<<nchN, 1024, 0, stream>>>(degi, off, csum, N);
    scan2_kernel<<<1, 1024, 0, stream>>>(csum, nchN);
    scan3_kernel<<<nchN, 1024, 0, stream>>>(off, csum, N, E);
    fill3_kernel<<<NB, 256, 0, stream>>>(staged, phist, off, srcl, nblocksP, N);

    int tiles     = (N + 15) / 16;
    int g2_blocks = (tiles + 3) / 4;
    int f_blocks  = (N + 63) / 64;

    gemm2_kernel<<<g2_blocks, 256, 0, stream>>>(x, wf, dis, bufA, N);
    fused_kernel<<<f_blocks, 256, 0, stream>>>(bufA, dis, off, srcl, B[0],
                                               wf + (size_t)1 * 8192, bufB, N);
    fused_kernel<<<f_blocks, 256, 0, stream>>>(bufB, dis, off, srcl, B[1],
                                               wf + (size_t)2 * 8192, bufA, N);
    fused_kernel<<<f_blocks, 256, 0, stream>>>(bufA, dis, off, srcl, B[2],
                                               wf + (size_t)3 * 8192, bufB, N);
    fused_final_kernel<<<f_blocks, 256, 0, stream>>>(bufB, dis, off, srcl, B[3],
                                                     wf, bo, out, N);
}

// Round 10
// 359.594 us; speedup vs baseline: 4.6096x; 4.6096x over previous
//
#include <hip/hip_runtime.h>
#include <hip/hip_bf16.h>
#include <math.h>

// ---------------------------------------------------------------------------
// GCN: 4 x [h = tanh(Dis (A+I) Dis (x W) + b)], then h @ W_out + b_out
// N=100k nodes, E=1M edges, D=64, D_OUT=16, all fp32.
// Setup: bucket partition (packed u32) -> LDS degrees -> CSR fill (LDS cursors),
//        srcl entries carry dst-local-64 in bits 17..22.
// Agg: SEGMENTED edge walk — quarter qq owns contiguous nodes 4qq..4qq+3 and
//      their contiguous CSR edge slice; batched-8 gathers (MLP), run-length
//      flush to exclusively-owned LDS rows (NO atomics).
// GEMMs: MFMA bf16 3-term split (AhBh+AlBh+AhBl), fp32 accumulate.
// ---------------------------------------------------------------------------

#define NBSHIFT 9   // bucket = dst >> 9  (512 nodes/bucket)

typedef __attribute__((ext_vector_type(8))) short short8;
typedef __attribute__((ext_vector_type(4))) float f32x4;

__device__ __forceinline__ float tanh_fast(float x) {
    float e = __expf(2.0f * x);
    return 1.0f - 2.0f / (e + 1.0f);
}
__device__ __forceinline__ unsigned short f2bf(float f) {   // RNE float->bf16
    unsigned u = __float_as_uint(f);
    return (unsigned short)((u + 0x7fff + ((u >> 16) & 1)) >> 16);
}
__device__ __forceinline__ float bf2f(unsigned short h) {
    return __uint_as_float((unsigned)h << 16);
}

// ---- generic 3-phase exclusive scan ----------------------------------------
__global__ void __launch_bounds__(1024) scan1_kernel(const int* __restrict__ in,
                                                     int* __restrict__ out,
                                                     int* __restrict__ csum, int n) {
    __shared__ int s[1024];
    int t = threadIdx.x;
    int i = blockIdx.x * 1024 + t;
    int v = (i < n) ? in[i] : 0;
    s[t] = v;
    __syncthreads();
    #pragma unroll
    for (int o = 1; o < 1024; o <<= 1) {
        int a = 0;
        if (t >= o) a = s[t - o];
        __syncthreads();
        if (t >= o) s[t] += a;
        __syncthreads();
    }
    if (i < n) out[i] = s[t] - v;          // exclusive
    if (t == 1023) csum[blockIdx.x] = s[1023];
}

__global__ void __launch_bounds__(1024) scan2_kernel(int* __restrict__ csum, int nc) {
    __shared__ int s[1024];
    int t = threadIdx.x;
    int v = (t < nc) ? csum[t] : 0;
    s[t] = v;
    __syncthreads();
    #pragma unroll
    for (int o = 1; o < 1024; o <<= 1) {
        int a = 0;
        if (t >= o) a = s[t - o];
        __syncthreads();
        if (t >= o) s[t] += a;
        __syncthreads();
    }
    if (t < nc) csum[t] = s[t] - v;        // exclusive
}

__global__ void __launch_bounds__(1024) scan3_kernel(int* __restrict__ out,
                                                     const int* __restrict__ csum,
                                                     int n, int total) {
    int i = blockIdx.x * 1024 + threadIdx.x;
    if (i < n) out[i] += csum[blockIdx.x];
    if (i == 0) out[n] = total;            // sentinel
}

// ---- bucket histogram ------------------------------------------------------
__global__ void __launch_bounds__(256) hist_kernel(const int* __restrict__ dst,
                                                   int* __restrict__ hist,
                                                   int E, int NB, int nblocks) {
    __shared__ int lh[256];
    int t = threadIdx.x;
    lh[t] = 0;
    __syncthreads();
    int base = blockIdx.x * 4096;
    int end = base + 4096; if (end > E) end = E;
    for (int i = base + t; i < end; i += 256)
        atomicAdd(&lh[dst[i] >> NBSHIFT], 1);
    __syncthreads();
    if (t < NB) hist[t * nblocks + blockIdx.x] = lh[t];
}

// ---- partition edges into bucket-major staging (packed u32) ----------------
// record = (local_dst[9b] << 17) | src[17b]   (N < 131072)
__global__ void __launch_bounds__(256) part_kernel(const int* __restrict__ src,
                                                   const int* __restrict__ dst,
                                                   const int* __restrict__ phist,
                                                   unsigned* __restrict__ staged,
                                                   int E, int NB, int nblocks) {
    __shared__ int lcur[256];
    int t = threadIdx.x;
    if (t < NB) lcur[t] = phist[t * nblocks + blockIdx.x];
    __syncthreads();
    int base = blockIdx.x * 4096;
    int end = base + 4096; if (end > E) end = E;
    for (int i = base + t; i < end; i += 256) {
        int d = dst[i];
        int b = d >> NBSHIFT;
        int pos = atomicAdd(&lcur[b], 1);
        staged[pos] = ((unsigned)(d & 511) << 17) | (unsigned)src[i];
    }
}

// ---- per-bucket degree count in LDS + dis = rsqrt(deg+1) -------------------
__global__ void __launch_bounds__(256) bdeg_kernel(const unsigned* __restrict__ staged,
                                                   const int* __restrict__ phist,
                                                   int* __restrict__ deg,
                                                   float* __restrict__ dis,
                                                   int nblocks, int n) {
    __shared__ int ldeg[512];
    int b = blockIdx.x, t = threadIdx.x;
    ldeg[t] = 0; ldeg[t + 256] = 0;
    __syncthreads();
    int r0 = phist[b * nblocks];
    int r1 = phist[(b + 1) * nblocks];
    for (int i = r0 + t; i < r1; i += 256)
        atomicAdd(&ldeg[staged[i] >> 17], 1);
    __syncthreads();
    int gbase = b << NBSHIFT;
    #pragma unroll
    for (int k = 0; k < 2; ++k) {
        int li = t + k * 256, gi = gbase + li;
        if (gi < n) {
            int d = ldeg[li];
            deg[gi] = d;
            dis[gi] = rsqrtf((float)d + 1.0f);
        }
    }
}

// ---- per-bucket CSR fill with LDS cursors ----------------------------------
// srcl entry = (dst&63)<<17 | src   (dst-local within any 64-aligned block)
__global__ void __launch_bounds__(256) fill3_kernel(const unsigned* __restrict__ staged,
                                                    const int* __restrict__ phist,
                                                    const int* __restrict__ off,
                                                    int* __restrict__ srcl,
                                                    int nblocks, int n) {
    __shared__ int lcur[512];
    int b = blockIdx.x, t = threadIdx.x;
    int gbase = b << NBSHIFT;
    #pragma unroll
    for (int k = 0; k < 2; ++k) {
        int li = t + k * 256, gi = gbase + li;
        lcur[li] = (gi < n) ? off[gi] : 0;
    }
    __syncthreads();
    int r0 = phist[b * nblocks];
    int r1 = phist[(b + 1) * nblocks];
    for (int i = r0 + t; i < r1; i += 256) {
        unsigned rec = staged[i];
        unsigned local9 = rec >> 17;
        int pos = atomicAdd(&lcur[local9], 1);
        srcl[pos] = (int)(((local9 & 63u) << 17) | (rec & 0x1FFFFu));
    }
}

// ---- W fragment prep: bf16 hi/lo frags arranged frag-major -----------------
__global__ void __launch_bounds__(256) wprep_kernel(const float* __restrict__ W0,
                                                    const float* __restrict__ W1,
                                                    const float* __restrict__ W2,
                                                    const float* __restrict__ W3,
                                                    short* __restrict__ wf) {
    const float* Ws[4] = {W0, W1, W2, W3};
    int l = blockIdx.x;
    const float* Wg = Ws[l];
    int t = threadIdx.x;
    int lane = t & 63;
    int ct = t >> 6;
    #pragma unroll
    for (int kk = 0; kk < 2; ++kk) {
        #pragma unroll
        for (int e = 0; e < 8; ++e) {
            int k = kk * 32 + (lane >> 4) * 8 + e;
            int c = ct * 16 + (lane & 15);
            float w = Wg[k * 64 + c];
            unsigned short hi = f2bf(w);
            unsigned short lo = f2bf(w - bf2f(hi));
            size_t b = ((size_t)l * 4 + ct) * 2 + kk;
            wf[((b * 2 + 0) * 64 + lane) * 8 + e] = (short)hi;
            wf[((b * 2 + 1) * 64 + lane) * 8 + e] = (short)lo;
        }
    }
}

// ---- W_out fragment prep (64x16, single col-tile), frag blocks 64..67 ------
__global__ void __launch_bounds__(64) wprep_out_kernel(const float* __restrict__ Wo,
                                                       short* __restrict__ wf) {
    int lane = threadIdx.x & 63;
    #pragma unroll
    for (int kk = 0; kk < 2; ++kk) {
        #pragma unroll
        for (int e = 0; e < 8; ++e) {
            int k = kk * 32 + (lane >> 4) * 8 + e;
            int c = lane & 15;
            float w = Wo[k * 16 + c];
            unsigned short hi = f2bf(w);
            unsigned short lo = f2bf(w - bf2f(hi));
            size_t b = 32 + kk;            // after 4 layers x 4ct x 2kk
            wf[((b * 2 + 0) * 64 + lane) * 8 + e] = (short)hi;
            wf[((b * 2 + 1) * 64 + lane) * 8 + e] = (short)lo;
        }
    }
}

// ---- bf16 split helper -----------------------------------------------------
#define SPLIT8(vA, vB, H, L) { \
    float _f[8] = {vA.x, vA.y, vA.z, vA.w, vB.x, vB.y, vB.z, vB.w}; \
    _Pragma("unroll") \
    for (int _e = 0; _e < 8; ++_e) { \
        unsigned short _h = f2bf(_f[_e]); \
        H[_e] = (short)_h; \
        L[_e] = (short)f2bf(_f[_e] - bf2f(_h)); \
    } }

// ---- MFMA gemm (layer 0): g[n][d] = dis[n] * sum_k x[n][k] * W[k][d] -------
__global__ void __launch_bounds__(256) gemm2_kernel(const float* __restrict__ in,
                                                    const short* __restrict__ wf,
                                                    const float* __restrict__ dis,
                                                    float* __restrict__ g, int n) {
    int t = threadIdx.x;
    int lane = t & 63;
    int wave = t >> 6;
    int c = lane & 15;
    int g4 = lane >> 4;

    short8 Bh[4][2], Bl[4][2];
    #pragma unroll
    for (int ct = 0; ct < 4; ++ct) {
        #pragma unroll
        for (int kk = 0; kk < 2; ++kk) {
            int b = (ct * 2 + kk) * 2;
            Bh[ct][kk] = *(const short8*)(wf + ((size_t)(b + 0) * 64 + lane) * 8);
            Bl[ct][kk] = *(const short8*)(wf + ((size_t)(b + 1) * 64 + lane) * 8);
        }
    }

    int tile = blockIdx.x * 4 + wave;
    int base = tile * 16;
    if (base >= n) return;

    const float4* ap = (const float4*)(in + (size_t)(base + c) * 64 + g4 * 8);
    float4 v00 = ap[0], v01 = ap[1];
    float4 v10 = ap[8], v11 = ap[9];

    short8 Ah0, Al0, Ah1, Al1;
    SPLIT8(v00, v01, Ah0, Al0);
    SPLIT8(v10, v11, Ah1, Al1);

    f32x4 acc[4];
    #pragma unroll
    for (int ct = 0; ct < 4; ++ct) {
        f32x4 a = {0.f, 0.f, 0.f, 0.f};
        a = __builtin_amdgcn_mfma_f32_16x16x32_bf16(Ah0, Bh[ct][0], a, 0, 0, 0);
        a = __builtin_amdgcn_mfma_f32_16x16x32_bf16(Ah1, Bh[ct][1], a, 0, 0, 0);
        a = __builtin_amdgcn_mfma_f32_16x16x32_bf16(Al0, Bh[ct][0], a, 0, 0, 0);
        a = __builtin_amdgcn_mfma_f32_16x16x32_bf16(Al1, Bh[ct][1], a, 0, 0, 0);
        a = __builtin_amdgcn_mfma_f32_16x16x32_bf16(Ah0, Bl[ct][0], a, 0, 0, 0);
        a = __builtin_amdgcn_mfma_f32_16x16x32_bf16(Ah1, Bl[ct][1], a, 0, 0, 0);
        acc[ct] = a;
    }

    f32x4 dvv = *(const f32x4*)(dis + base + g4 * 4);
    #pragma unroll
    for (int ct = 0; ct < 4; ++ct) {
        #pragma unroll
        for (int r = 0; r < 4; ++r) {
            g[(size_t)(base + g4 * 4 + r) * 64 + ct * 16 + c] = dvv[r] * acc[ct][r];
        }
    }
}

// ---- agg phase: segmented edge walk, batched-8 gathers, no atomics ---------
// Quarter qq owns nodes base+4qq..base+4qq+3 (contiguous CSR slice) and
// exclusively owns hs rows 4qq..4qq+3 during the edge walk.
#define FLUSH_ACC() { \
    float* hrow = &hs[rowbase + curdl][r * 4]; \
    hrow[0] += acc.x; hrow[1] += acc.y; hrow[2] += acc.z; hrow[3] += acc.w; \
    acc.x = 0.f; acc.y = 0.f; acc.z = 0.f; acc.w = 0.f; }

__device__ __forceinline__ void agg_phase(float (*hs)[68],
                                          const float* __restrict__ g_in,
                                          const float* __restrict__ dis,
                                          const int* __restrict__ off,
                                          const int* __restrict__ srcl,
                                          const float* __restrict__ bias,
                                          int base, int n, int t) {
    int r = t & 15;                        // lane-in-quarter (float4 column)
    int qq = t >> 4;                       // quarter 0..15
    const float4* gv = (const float4*)g_in;
    int rowbase = qq * 4;

    // self-term init: quarter qq inits its own 4 rows
    #pragma unroll
    for (int d = 0; d < 4; ++d) {
        int node = base + rowbase + d;
        if (node < n) {
            float4 sv = gv[(size_t)node * 16 + r];
            hs[rowbase + d][r * 4 + 0] = sv.x;
            hs[rowbase + d][r * 4 + 1] = sv.y;
            hs[rowbase + d][r * 4 + 2] = sv.z;
            hs[rowbase + d][r * 4 + 3] = sv.w;
        }
    }
    // no barrier needed: rows are exclusively owned through the edge walk

    int lo = base + rowbase;     if (lo > n) lo = n;
    int hi2 = base + rowbase + 4; if (hi2 > n) hi2 = n;
    int e = off[lo], eEnd = off[hi2];

    int curdl = 0;
    float4 acc = {0.f, 0.f, 0.f, 0.f};

    while (e + 8 <= eEnd) {
        unsigned rc[8];
        #pragma unroll
        for (int j = 0; j < 8; ++j) rc[j] = (unsigned)srcl[e + j];
        float4 gg[8];
        #pragma unroll
        for (int j = 0; j < 8; ++j)
            gg[j] = gv[(size_t)(rc[j] & 0x1FFFFu) * 16 + r];
        #pragma unroll
        for (int j = 0; j < 8; ++j) {
            int dl = (int)((rc[j] >> 17) & 3u);
            if (dl != curdl) { FLUSH_ACC(); curdl = dl; }
            acc.x += gg[j].x; acc.y += gg[j].y;
            acc.z += gg[j].z; acc.w += gg[j].w;
        }
        e += 8;
    }
    for (; e < eEnd; ++e) {
        unsigned rec = (unsigned)srcl[e];
        float4 a = gv[(size_t)(rec & 0x1FFFFu) * 16 + r];
        int dl = (int)((rec >> 17) & 3u);
        if (dl != curdl) { FLUSH_ACC(); curdl = dl; }
        acc.x += a.x; acc.y += a.y; acc.z += a.z; acc.w += a.w;
    }
    FLUSH_ACC();
    __syncthreads();

    // transform: tanh(dn*sum + b)
    float4 b4 = ((const float4*)bias)[r];
    #pragma unroll
    for (int p = 0; p < 4; ++p) {
        int nl = p * 16 + qq;
        int node = base + nl;
        if (node < n) {
            float dn = dis[node];
            hs[nl][r * 4 + 0] = tanh_fast(fmaf(dn, hs[nl][r * 4 + 0], b4.x));
            hs[nl][r * 4 + 1] = tanh_fast(fmaf(dn, hs[nl][r * 4 + 1], b4.y));
            hs[nl][r * 4 + 2] = tanh_fast(fmaf(dn, hs[nl][r * 4 + 2], b4.z));
            hs[nl][r * 4 + 3] = tanh_fast(fmaf(dn, hs[nl][r * 4 + 3], b4.w));
        }
    }
    __syncthreads();
}

// ---- fused: agg -> g_{l+1} = dis * (h @ W) via MFMA ------------------------
__global__ void __launch_bounds__(256) fused_kernel(const float* __restrict__ g_in,
                                                    const float* __restrict__ dis,
                                                    const int* __restrict__ off,
                                                    const int* __restrict__ srcl,
                                                    const float* __restrict__ bias,
                                                    const short* __restrict__ wfn,
                                                    float* __restrict__ g_out, int n) {
    __shared__ float hs[64][68];
    int t = threadIdx.x;
    int base = blockIdx.x * 64;

    agg_phase(hs, g_in, dis, off, srcl, bias, base, n, t);

    int lane = t & 63;
    int wave = t >> 6;
    int c = lane & 15;
    int g4 = lane >> 4;
    int obase = base + wave * 16;
    if (obase >= n) return;

    short8 Bh[4][2], Bl[4][2];
    #pragma unroll
    for (int ct = 0; ct < 4; ++ct) {
        #pragma unroll
        for (int kk = 0; kk < 2; ++kk) {
            int b = (ct * 2 + kk) * 2;
            Bh[ct][kk] = *(const short8*)(wfn + ((size_t)(b + 0) * 64 + lane) * 8);
            Bl[ct][kk] = *(const short8*)(wfn + ((size_t)(b + 1) * 64 + lane) * 8);
        }
    }

    const float* hr = &hs[wave * 16 + c][0];
    float4 v00 = *(const float4*)(hr + g4 * 8);
    float4 v01 = *(const float4*)(hr + g4 * 8 + 4);
    float4 v10 = *(const float4*)(hr + g4 * 8 + 32);
    float4 v11 = *(const float4*)(hr + g4 * 8 + 36);

    short8 Ah0, Al0, Ah1, Al1;
    SPLIT8(v00, v01, Ah0, Al0);
    SPLIT8(v10, v11, Ah1, Al1);

    f32x4 acc[4];
    #pragma unroll
    for (int ct = 0; ct < 4; ++ct) {
        f32x4 a = {0.f, 0.f, 0.f, 0.f};
        a = __builtin_amdgcn_mfma_f32_16x16x32_bf16(Ah0, Bh[ct][0], a, 0, 0, 0);
        a = __builtin_amdgcn_mfma_f32_16x16x32_bf16(Ah1, Bh[ct][1], a, 0, 0, 0);
        a = __builtin_amdgcn_mfma_f32_16x16x32_bf16(Al0, Bh[ct][0], a, 0, 0, 0);
        a = __builtin_amdgcn_mfma_f32_16x16x32_bf16(Al1, Bh[ct][1], a, 0, 0, 0);
        a = __builtin_amdgcn_mfma_f32_16x16x32_bf16(Ah0, Bl[ct][0], a, 0, 0, 0);
        a = __builtin_amdgcn_mfma_f32_16x16x32_bf16(Ah1, Bl[ct][1], a, 0, 0, 0);
        acc[ct] = a;
    }

    f32x4 dvv = *(const f32x4*)(dis + obase + g4 * 4);
    #pragma unroll
    for (int ct = 0; ct < 4; ++ct) {
        #pragma unroll
        for (int rr = 0; rr < 4; ++rr) {
            g_out[(size_t)(obase + g4 * 4 + rr) * 64 + ct * 16 + c] = dvv[rr] * acc[ct][rr];
        }
    }
}

// ---- fused final: agg(layer 3) -> out = h @ Wo + bo via MFMA ---------------
__global__ void __launch_bounds__(256) fused_final_kernel(const float* __restrict__ g_in,
                                                          const float* __restrict__ dis,
                                                          const int* __restrict__ off,
                                                          const int* __restrict__ srcl,
                                                          const float* __restrict__ bias,
                                                          const short* __restrict__ wf,
                                                          const float* __restrict__ bo,
                                                          float* __restrict__ out, int n) {
    __shared__ float hs[64][68];
    int t = threadIdx.x;
    int base = blockIdx.x * 64;

    agg_phase(hs, g_in, dis, off, srcl, bias, base, n, t);

    int lane = t & 63;
    int wave = t >> 6;
    int c = lane & 15;
    int g4 = lane >> 4;
    int obase = base + wave * 16;
    if (obase >= n) return;

    short8 Bh2[2], Bl2[2];
    #pragma unroll
    for (int kk = 0; kk < 2; ++kk) {
        size_t b = 32 + kk;
        Bh2[kk] = *(const short8*)(wf + ((b * 2 + 0) * 64 + lane) * 8);
        Bl2[kk] = *(const short8*)(wf + ((b * 2 + 1) * 64 + lane) * 8);
    }

    const float* hr = &hs[wave * 16 + c][0];
    float4 v00 = *(const float4*)(hr + g4 * 8);
    float4 v01 = *(const float4*)(hr + g4 * 8 + 4);
    float4 v10 = *(const float4*)(hr + g4 * 8 + 32);
    float4 v11 = *(const float4*)(hr + g4 * 8 + 36);

    short8 Ah0, Al0, Ah1, Al1;
    SPLIT8(v00, v01, Ah0, Al0);
    SPLIT8(v10, v11, Ah1, Al1);

    float bv = bo[c];
    f32x4 a = {bv, bv, bv, bv};
    a = __builtin_amdgcn_mfma_f32_16x16x32_bf16(Ah0, Bh2[0], a, 0, 0, 0);
    a = __builtin_amdgcn_mfma_f32_16x16x32_bf16(Ah1, Bh2[1], a, 0, 0, 0);
    a = __builtin_amdgcn_mfma_f32_16x16x32_bf16(Al0, Bh2[0], a, 0, 0, 0);
    a = __builtin_amdgcn_mfma_f32_16x16x32_bf16(Al1, Bh2[1], a, 0, 0, 0);
    a = __builtin_amdgcn_mfma_f32_16x16x32_bf16(Ah0, Bl2[0], a, 0, 0, 0);
    a = __builtin_amdgcn_mfma_f32_16x16x32_bf16(Ah1, Bl2[1], a, 0, 0, 0);

    #pragma unroll
    for (int rr = 0; rr < 4; ++rr) {
        out[(size_t)(obase + g4 * 4 + rr) * 16 + c] = a[rr];
    }
}

// ---------------------------------------------------------------------------
extern "C" void kernel_launch(void* const* d_in, const int* in_sizes, int n_in,
                              void* d_out, int out_size, void* d_ws, size_t ws_size,
                              hipStream_t stream) {
    const float* x     = (const float*)d_in[0];
    const int*   ei    = (const int*)d_in[1];   // (2, E) int32
    const float* W[4]  = {(const float*)d_in[2], (const float*)d_in[4],
                          (const float*)d_in[6], (const float*)d_in[8]};
    const float* B[4]  = {(const float*)d_in[3], (const float*)d_in[5],
                          (const float*)d_in[7], (const float*)d_in[9]};
    const float* Wo    = (const float*)d_in[10];
    const float* bo    = (const float*)d_in[11];
    float* out         = (float*)d_out;

    const int N = in_sizes[0] / 64;
    const int E = in_sizes[1] / 2;
    const int* srcp = ei;
    const int* dstp = ei + E;

    const int NB       = (N + (1 << NBSHIFT) - 1) >> NBSHIFT;  // 196
    const int nblocksP = (E + 4095) / 4096;                    // 245
    const int NH       = NB * nblocksP;

    char* w = (char*)d_ws;
    size_t o = 0;
    auto alloc = [&](size_t bytes) { void* p = w + o; o = (o + bytes + 255) & ~(size_t)255; return p; };
    float*    dis    = (float*)alloc((size_t)N * 4);
    int*      degi   = (int*)  alloc((size_t)N * 4);
    int*      off    = (int*)  alloc((size_t)(N + 1) * 4);
    int*      csum   = (int*)  alloc(4096);
    int*      srcl   = (int*)  alloc((size_t)E * 4);
    int*      hist   = (int*)  alloc((size_t)NH * 4);
    int*      phist  = (int*)  alloc((size_t)(NH + 1) * 4);
    short*    wf     = (short*)alloc((size_t)70 * 1024);      // 68 x 1KB frag blocks
    float*    bufA   = (float*)alloc((size_t)N * 64 * 4);
    float*    bufB   = (float*)alloc((size_t)N * 64 * 4);
    unsigned* staged = (unsigned*)bufA;    // reuse (4MB < 25.6MB), consumed pre-gemm

    int nchN = (N + 1023) / 1024;
    int nchH = (NH + 1023) / 1024;

    wprep_kernel<<<4, 256, 0, stream>>>(W[0], W[1], W[2], W[3], wf);
    wprep_out_kernel<<<1, 64, 0, stream>>>(Wo, wf);
    hist_kernel<<<nblocksP, 256, 0, stream>>>(dstp, hist, E, NB, nblocksP);
    scan1_kernel<<<nchH, 1024, 0, stream>>>(hist, phist, csum, NH);
    scan2_kernel<<<1, 1024, 0, stream>>>(csum, nchH);
    scan3_kernel<<<nchH, 1024, 0, stream>>>(phist, csum, NH, E);
    part_kernel<<<nblocksP, 256, 0, stream>>>(srcp, dstp, phist, staged, E, NB, nblocksP);
    bdeg_kernel<<<NB, 256, 0, stream>>>(staged, phist, degi, dis, nblocksP, N);
    scan1_kernel<<<nchN, 1024, 0, stream>>>(degi, off, csum, N);
    scan2_kernel<<<1, 1024, 0, stream>>>(csum, nchN);
    scan3_kernel<<<nchN, 1024, 0, stream>>>(off, csum, N, E);
    fill3_kernel<<<NB, 256, 0, stream>>>(staged, phist, off, srcl, nblocksP, N);

    int tiles     = (N + 15) / 16;
    int g2_blocks = (tiles + 3) / 4;
    int f_blocks  = (N + 63) / 64;

    gemm2_kernel<<<g2_blocks, 256, 0, stream>>>(x, wf, dis, bufA, N);
    fused_kernel<<<f_blocks, 256, 0, stream>>>(bufA, dis, off, srcl, B[0],
                                               wf + (size_t)1 * 8192, bufB, N);
    fused_kernel<<<f_blocks, 256, 0, stream>>>(bufB, dis, off, srcl, B[1],
                                               wf + (size_t)2 * 8192, bufA, N);
    fused_kernel<<<f_blocks, 256, 0, stream>>>(bufA, dis, off, srcl, B[2],
                                               wf + (size_t)3 * 8192, bufB, N);
    fused_final_kernel<<<f_blocks, 256, 0, stream>>>(bufB, dis, off, srcl, B[3],
                                                     wf, bo, out, N);
}